// Round 3
// baseline (151.620 us; speedup 1.0000x reference)
//
#include <hip/hip_runtime.h>

// Aggregation: input [32,16,16,1024] f32 NHWC, weight [32,256,9,256] f32,
// out [32,1024,16,16] f32.
//
// Index algebra (verified in Round 0): out[n, g*256+cw, l] =
//   sum_q weight[n,cw,q,l] * input[n, hi, wj, c]  where
//   m  = 9*(cw&3) + q          (wave-uniform)
//   p  = m>>2 ; di = p/3 ; dj = p%3
//   c  = (m&3)*256 + l         -> contiguous 256-float chunk per (cw,q)
//   hi = 4g + (cw>>6) + di - 1 ; wj = ((cw>>2)&15) + dj - 1 ; 0 if OOB.
// Since p and the channel chunk are wave-uniform, ALL memory ops vectorize
// to float4 with wave-uniform predicates.
//
// Layout: block = 256 thr = 4 cw (one wave each) x 64 lanes; lane t owns
// l = 4t..4t+3 (one float4). Grid = 32 n * 64 cw-blocks = 2048, %8==0 ->
// simple XCD swizzle is bijective; each XCD gets 4 consecutive n (4 MB
// input working set, fits its private L2).

__global__ __launch_bounds__(256)
void Aggregation_33320356282418_kernel(const float* __restrict__ input,
                                       const float* __restrict__ weight,
                                       float* __restrict__ out) {
    // XCD-aware swizzle: XCD x gets contiguous block range [x*256,(x+1)*256)
    const int b   = blockIdx.x;             // 0..2047
    const int blk = (b & 7) * 256 + (b >> 3);

    const int cb  = blk & 63;               // cw-block 0..63
    const int n   = blk >> 6;               // 0..31
    const int tid = threadIdx.x;
    const int cwi = tid >> 6;               // 0..3  (= wave id)
    const int t   = tid & 63;               // lane
    const int cw  = cb * 4 + cwi;

    const int hbase = cw >> 6;              // 0..3
    const int w0    = (cw >> 2) & 15;       // 0..15
    const int mb    = 9 * (cw & 3);

    const float4* __restrict__ inp4 =
        (const float4*)(input + (size_t)n * (16 * 16 * 1024));
    const float4* __restrict__ w4 =
        (const float4*)(weight + ((size_t)(n * 256 + cw) * 9) * 256);
    float4* __restrict__ o4 =
        (float4*)(out + ((size_t)n * 1024 + cw) * 256);

    float4 acc[4];
#pragma unroll
    for (int g = 0; g < 4; ++g) acc[g] = make_float4(0.f, 0.f, 0.f, 0.f);

#pragma unroll
    for (int q = 0; q < 9; ++q) {
        const int m  = mb + q;
        const int p  = m >> 2;              // 0..8
        const int di = p / 3;
        const int dj = p - 3 * di;
        const int wj = w0 + dj - 1;
        const bool wok = (unsigned)wj < 16u;
        const int cu = (m & 3) * 64;        // float4 units into the pixel row

        const float4 wq = w4[q * 64 + t];

#pragma unroll
        for (int g = 0; g < 4; ++g) {
            const int hi = 4 * g + hbase + di - 1;
            float4 v = make_float4(0.f, 0.f, 0.f, 0.f);
            if (wok && (unsigned)hi < 16u) {
                v = inp4[(hi * 16 + wj) * 256 + cu + t];
            }
            acc[g].x = fmaf(wq.x, v.x, acc[g].x);
            acc[g].y = fmaf(wq.y, v.y, acc[g].y);
            acc[g].z = fmaf(wq.z, v.z, acc[g].z);
            acc[g].w = fmaf(wq.w, v.w, acc[g].w);
        }
    }

#pragma unroll
    for (int g = 0; g < 4; ++g) {
        o4[g * (256 * 256 / 4) + t] = acc[g];   // C = g*256 + cw
    }
}

extern "C" void kernel_launch(void* const* d_in, const int* in_sizes, int n_in,
                              void* d_out, int out_size, void* d_ws, size_t ws_size,
                              hipStream_t stream) {
    const float* input  = (const float*)d_in[0];   // [32,16,16,1024]
    const float* weight = (const float*)d_in[1];   // [32,256,9,256]
    float* out = (float*)d_out;                    // [32,1024,16,16]

    dim3 grid(32 * 64);    // (n, cw-block-of-4)
    dim3 block(256);       // 4 waves: one cw each
    hipLaunchKernelGGL(Aggregation_33320356282418_kernel, grid, block, 0, stream,
                       input, weight, out);
}